// Round 14
// baseline (384.401 us; speedup 1.0000x reference)
//
#include <hip/hip_runtime.h>
#include <hip/hip_bf16.h>

#define B_    8
#define N_    2048
#define CIN_  64
#define D_    128
#define DFF_  512
#define DOUT_ 256
#define S_    512
#define H_    4
#define HD_   32
#define EPS_  1e-5f

typedef unsigned short u16;
typedef unsigned int u32;
typedef unsigned long long u64;
typedef __attribute__((ext_vector_type(8))) short short8v;  // 8 bf16
typedef __attribute__((ext_vector_type(4))) float f32x4;

__device__ __forceinline__ u16 f2bu(float f) {
  __hip_bfloat16 h = __float2bfloat16(f);
  return *(u16*)&h;
}
__device__ __forceinline__ float bu2f(u16 u) {
  __hip_bfloat16 h = *(__hip_bfloat16*)&u;
  return __bfloat162float(h);
}

// ---------------------------------------------------------------------------
// Weight prep. SC folds 1/sqrt(hd) AND log2(e): attention softmax runs in
// exp2 domain (bare v_exp_f32), verified bit-adequate in R7-R13.
// ---------------------------------------------------------------------------
#define OW_QKV 0
#define OW_O   49152
#define OW_1   65536
#define OW_2   131072
#define OW_FC  196608
#define OW_CAT 237568
#define NW_TOT 249856

__global__ __launch_bounds__(256) void prep_kernel(
    const float* __restrict__ Wq, const float* __restrict__ bq,
    const float* __restrict__ Wk, const float* __restrict__ bk,
    const float* __restrict__ Wv, const float* __restrict__ bv,
    const float* __restrict__ Wo, const float* __restrict__ W1,
    const float* __restrict__ W2, const float* __restrict__ Wfc,
    const float* __restrict__ bfc, const float* __restrict__ Wp,
    const float* __restrict__ bp, const float* __restrict__ Wpos,
    const float* __restrict__ bpos, const float* __restrict__ g1,
    const float* __restrict__ be1, const float* __restrict__ m1,
    const float* __restrict__ v1, const float* __restrict__ g2,
    const float* __restrict__ bb2, const float* __restrict__ m2,
    const float* __restrict__ v2, u16* __restrict__ wb,
    float* __restrict__ fb) {
  const float SC = 0.1767766952966369f * 1.4426950408889634f;  // /sqrt(hd)*log2e
  int i = blockIdx.x * 256 + threadIdx.x;
  if (i < OW_O) {  // Wqkv [384][128]
    int n = i >> 7, k = i & 127;
    float v = (n < 128) ? Wq[i] * SC
                        : (n < 256) ? Wk[(n - 128) * 128 + k]
                                    : Wv[(n - 256) * 128 + k];
    wb[OW_QKV + i] = f2bu(v);
  } else if (i < OW_1) {
    wb[i] = f2bu(Wo[i - OW_O]);
  } else if (i < OW_2) {
    wb[i] = f2bu(W1[i - OW_1]);
  } else if (i < OW_FC) {
    wb[i] = f2bu(W2[i - OW_2]);
  } else if (i < OW_CAT) {  // Wfc [256][160] (pad 131->160)
    int j = i - OW_FC;
    int n = j / 160, c = j % 160;
    wb[i] = f2bu(c < 131 ? Wfc[n * 131 + c] : 0.f);
  } else if (i < NW_TOT) {  // Wcat [128][96]: BN1-scaled Wp | Wpos | 0
    int j = i - OW_CAT;
    int d = j / 96, c = j % 96;
    float v;
    if (c < 64) v = Wp[d * 64 + c] * (g1[d] * rsqrtf(v1[d] + EPS_));
    else if (c < 67) v = Wpos[d * 3 + (c - 64)];
    else v = 0.f;
    wb[i] = f2bu(v);
  } else if (i < NW_TOT + 384) {  // bqkv
    int n = i - NW_TOT;
    fb[n] = (n < 128) ? bq[n] * SC : (n < 256) ? bk[n - 128] : bv[n - 256];
  } else if (i < NW_TOT + 512) {  // bias_x
    int d = i - (NW_TOT + 384);
    float s1 = g1[d] * rsqrtf(v1[d] + EPS_);
    fb[384 + d] = (bp[d] - m1[d]) * s1 + be1[d] + bpos[d];
  } else if (i < NW_TOT + 768) {  // fc_scale
    int n = i - (NW_TOT + 512);
    fb[512 + n] = g2[n] * rsqrtf(v2[n] + EPS_);
  } else if (i < NW_TOT + 1024) {  // fc_shift
    int n = i - (NW_TOT + 768);
    float s = g2[n] * rsqrtf(v2[n] + EPS_);
    fb[768 + n] = bfc[n] * s + bb2[n] - m2[n] * s;
  }
}

// ---------------------------------------------------------------------------
// FPS slice (4 waves, 8 pts/lane): steps [s0,s1) for batch b, hosted as
// extra blocks in the pipeline kernels (state in d_ws). numpy-exact f32
// arithmetic, first-occurrence argmax.
// R14: wave-level winner found by carrying the FULL tuple {key,x,y,z}
// through the DPP reduce (key = dist_bits<<32 | ~idx, unique -> plain u64
// max == (dist, smallest idx) order). Removes the ballot/ffs/4x dynamic
// v_readlane serial tail; lane 63 writes the tuple directly to LDS.
// ---------------------------------------------------------------------------
#define FPS_SMEM 320

template <int CTRL, int RM>
__device__ __forceinline__ void dppsel(u64& key, float& x, float& y, float& z) {
  int klo = __builtin_amdgcn_update_dpp((int)(u32)key, (int)(u32)key,
                                        CTRL, RM, 0xF, true);
  int khi = __builtin_amdgcn_update_dpp((int)(u32)(key >> 32),
                                        (int)(u32)(key >> 32), CTRL, RM, 0xF,
                                        true);
  int sx = __builtin_amdgcn_update_dpp(__float_as_int(x), __float_as_int(x),
                                       CTRL, RM, 0xF, true);
  int sy = __builtin_amdgcn_update_dpp(__float_as_int(y), __float_as_int(y),
                                       CTRL, RM, 0xF, true);
  int sz = __builtin_amdgcn_update_dpp(__float_as_int(z), __float_as_int(z),
                                       CTRL, RM, 0xF, true);
  u64 sk = ((u64)(u32)khi << 32) | (u32)klo;
  bool c = sk > key;
  key = c ? sk : key;
  x = c ? __int_as_float(sx) : x;
  y = c ? __int_as_float(sy) : y;
  z = c ? __int_as_float(sz) : z;
}

__device__ __forceinline__ void fps_slice(
    char* smem, int b, const float* __restrict__ xyz,
    float* __restrict__ dist_ws, int* __restrict__ far_ws,
    int* __restrict__ idx_out, float* __restrict__ out0, int s0, int s1) {
  u64* keys = (u64*)smem;            // [2][4]
  float* crd = (float*)(smem + 64);  // [2][4][3]
  const int t = threadIdx.x, w = t >> 6, lane = t & 63;
  const float* xb = xyz + (size_t)b * 3 * N_;
  const int base = (w * 64 + lane) * 8;
  float* dw = dist_ws + b * N_;
  float px[8], py[8], pz[8], dist[8];
#pragma unroll
  for (int j = 0; j < 8; j++) {
    px[j] = xb[base + j];
    py[j] = xb[N_ + base + j];
    pz[j] = xb[2 * N_ + base + j];
    dist[j] = 1e10f;
  }
  if (s0 != 0) {
#pragma unroll
    for (int j = 0; j < 8; j++) dist[j] = dw[base + j];
  }
  int far = (s0 == 0) ? 0 : far_ws[b];
  float cx = xb[far], cy = xb[N_ + far], cz = xb[2 * N_ + far];
  for (int s = s0; s < s1; s++) {
    if (t == 0) {
      idx_out[b * S_ + s] = far;
      out0[(size_t)b * 3 * S_ + s] = cx;
      out0[(size_t)b * 3 * S_ + S_ + s] = cy;
      out0[(size_t)b * 3 * S_ + 2 * S_ + s] = cz;
    }
    float best = -1.0f, bx = 0.f, by = 0.f, bz = 0.f;
    int bestp = 0;
#pragma unroll
    for (int j = 0; j < 8; j++) {
      float dx = __fsub_rn(px[j], cx);
      float dy = __fsub_rn(py[j], cy);
      float dz = __fsub_rn(pz[j], cz);
      float d = __fadd_rn(__fadd_rn(__fmul_rn(dx, dx), __fmul_rn(dy, dy)),
                          __fmul_rn(dz, dz));
      float nd = fminf(dist[j], d);
      dist[j] = nd;
      if (nd > best) {
        best = nd; bestp = base + j;  // ascending j: first max
        bx = px[j]; by = py[j]; bz = pz[j];
      }
    }
    // wave-wide winner: tuple-select DPP reduce; lane 63 holds the winner.
    // key = dist_bits<<32 | ~idx (unique) -> u64 max == numpy argmax order.
    u64 wkey = ((u64)__float_as_uint(best) << 32) |
               (unsigned)(0xFFFFFFFFu - (unsigned)bestp);
    dppsel<0x111, 0xF>(wkey, bx, by, bz);  // row_shr:1
    dppsel<0x112, 0xF>(wkey, bx, by, bz);  // row_shr:2
    dppsel<0x114, 0xF>(wkey, bx, by, bz);  // row_shr:4
    dppsel<0x118, 0xF>(wkey, bx, by, bz);  // row_shr:8
    dppsel<0x142, 0xA>(wkey, bx, by, bz);  // row_bcast:15
    dppsel<0x143, 0xC>(wkey, bx, by, bz);  // row_bcast:31
    if (lane == 63) {
      int sb = (s & 1) * 4 + w;
      keys[sb] = wkey;
      crd[sb * 3 + 0] = bx;
      crd[sb * 3 + 1] = by;
      crd[sb * 3 + 2] = bz;
    }
    asm volatile("s_waitcnt lgkmcnt(0)" ::: "memory");
    __builtin_amdgcn_s_barrier();
    asm volatile("" ::: "memory");
    const int q0 = (s & 1) * 4;
    u64 k0 = keys[q0], k1 = keys[q0 + 1], k2 = keys[q0 + 2], k3 = keys[q0 + 3];
    const f32x4* crd4 = (const f32x4*)(crd + q0 * 3);
    f32x4 v0 = crd4[0], v1 = crd4[1], v2 = crd4[2];
    // candidates: c0=(v0.xyz) c1=(v0.w,v1.xy) c2=(v1.zw,v2.x) c3=(v2.yzw)
    bool c01 = k0 >= k1;
    u64 ka = c01 ? k0 : k1;
    float xa = c01 ? v0[0] : v0[3], ya = c01 ? v0[1] : v1[0],
          za = c01 ? v0[2] : v1[1];
    bool c23 = k2 >= k3;
    u64 kb = c23 ? k2 : k3;
    float xv = c23 ? v1[2] : v2[1], yv = c23 ? v1[3] : v2[2],
          zv = c23 ? v2[0] : v2[3];
    bool cf = ka >= kb;
    u64 kk = cf ? ka : kb;
    cx = cf ? xa : xv; cy = cf ? ya : yv; cz = cf ? za : zv;
    far = (int)(0xFFFFFFFFu - (unsigned)kk);
  }
#pragma unroll
  for (int j = 0; j < 8; j++) dw[base + j] = dist[j];
  if (t == 0) far_ws[b] = far;
}

// ---------------------------------------------------------------------------
// Tiled bf16 MFMA GEMM template (+ FPS co-blocks at blockIdx < fpsnb).
// C[128 x 128] tile per block, 4 waves, 16x16x32 MFMA. (R9-R11 verified.)
// LDS padded to 84 KB (R11): FPS co-blocks get dedicated CUs; GEMM hosts
// are slice-bound so the 1-block/CU cost is hidden.
// ---------------------------------------------------------------------------
template <int K, int KC, int ASTAGE, int EPI>
__global__ __launch_bounds__(256) void gemm_k(
    const u16* __restrict__ A, const u16* __restrict__ W,
    const float* __restrict__ srcf0, const float* __restrict__ srcf1,
    const int* __restrict__ fidx, const float* __restrict__ p0,
    const float* __restrict__ p1, const float* __restrict__ p2,
    const u16* __restrict__ resid, u16* __restrict__ outb,
    float* __restrict__ outf, int ntn, int fpsnb, int s0, int s1,
    const float* fxyz, float* fdist, int* ffar, int* fidxo, float* fout0) {
  constexpr int KP = KC + 8;
  constexpr int GEMM_SMEM = 2 * 128 * KP * 2;
  constexpr int SMEM = GEMM_SMEM > 86016 ? GEMM_SMEM : 86016;  // CU fence
  __shared__ __align__(16) char smem[SMEM];
  if ((int)blockIdx.x < fpsnb) {
    fps_slice(smem, blockIdx.x, fxyz, fdist, ffar, fidxo, fout0, s0, s1);
    return;
  }
  u16 (*As)[KP] = (u16 (*)[KP])smem;
  u16 (*Ws)[KP] = (u16 (*)[KP])(smem + 128 * KP * 2);
  const int bid = blockIdx.x - fpsnb;
  const int mt = bid / ntn, nt = bid % ntn;
  const int t = threadIdx.x, w = t >> 6, lane = t & 63;
  const int g = lane >> 4, lr = lane & 15;

  f32x4 acc[2][8];
#pragma unroll
  for (int qf = 0; qf < 2; qf++)
#pragma unroll
    for (int nf = 0; nf < 8; nf++) acc[qf][nf] = {0.f, 0.f, 0.f, 0.f};

  for (int kc = 0; kc < K / KC; kc++) {
    __syncthreads();
    for (int i = t; i < 128 * (KC / 8); i += 256) {
      int row = i / (KC / 8), c8 = i % (KC / 8);
      *(short8v*)&Ws[row][c8 * 8] =
          *(const short8v*)(W + (size_t)(nt * 128 + row) * K + kc * KC + c8 * 8);
    }
    if constexpr (ASTAGE == 0) {
      for (int i = t; i < 128 * (KC / 8); i += 256) {
        int row = i / (KC / 8), c8 = i % (KC / 8);
        *(short8v*)&As[row][c8 * 8] =
            *(const short8v*)(A + (size_t)(mt * 128 + row) * K + kc * KC + c8 * 8);
      }
    } else if constexpr (ASTAGE == 1) {
      int bb = (mt * 128) >> 11, n0 = (mt * 128) & (N_ - 1);
      for (int i = t; i < 96 * 128; i += 256) {
        int c = i >> 7, n = i & 127;
        float v;
        if (c < 64) v = srcf0[((size_t)bb * CIN_ + c) * N_ + n0 + n];
        else if (c < 67) v = srcf1[((size_t)bb * 3 + (c - 64)) * N_ + n0 + n];
        else v = 0.f;
        As[n][c] = f2bu(v);
      }
    } else {  // ASTAGE == 2
      int bb = (mt * 128) >> 9, sq0 = (mt * 128) & (S_ - 1);
      for (int i = t; i < 128 * 20; i += 256) {
        int row = i / 20, c8 = i % 20;
        int id = fidx[bb * S_ + sq0 + row];
        short8v val;
        if (c8 < 16) {
          val = *(const short8v*)(A + ((size_t)bb * N_ + id) * D_ + c8 * 8);
        } else if (c8 == 16) {
          val = short8v{0, 0, 0, 0, 0, 0, 0, 0};
          val[0] = (short)f2bu(srcf1[((size_t)bb * 3 + 0) * N_ + id]);
          val[1] = (short)f2bu(srcf1[((size_t)bb * 3 + 1) * N_ + id]);
          val[2] = (short)f2bu(srcf1[((size_t)bb * 3 + 2) * N_ + id]);
        } else {
          val = short8v{0, 0, 0, 0, 0, 0, 0, 0};
        }
        *(short8v*)&As[row][c8 * 8] = val;
      }
    }
    __syncthreads();
#pragma unroll
    for (int ks = 0; ks < KC / 32; ks++) {
      short8v a0 = *(const short8v*)&As[w * 32 + lr][ks * 32 + 8 * g];
      short8v a1 = *(const short8v*)&As[w * 32 + 16 + lr][ks * 32 + 8 * g];
#pragma unroll
      for (int nf = 0; nf < 8; nf++) {
        short8v bb = *(const short8v*)&Ws[nf * 16 + lr][ks * 32 + 8 * g];
        acc[0][nf] = __builtin_amdgcn_mfma_f32_16x16x32_bf16(a0, bb, acc[0][nf], 0, 0, 0);
        acc[1][nf] = __builtin_amdgcn_mfma_f32_16x16x32_bf16(a1, bb, acc[1][nf], 0, 0, 0);
      }
    }
  }

  if constexpr (EPI == 3) {  // bias + residual + LayerNorm (ntn==1)
#pragma unroll
    for (int qf = 0; qf < 2; qf++) {
#pragma unroll
      for (int i = 0; i < 4; i++) {
        int m = mt * 128 + w * 32 + qf * 16 + 4 * g + i;
        float v[8], sm = 0.f, sq = 0.f;
#pragma unroll
        for (int nf = 0; nf < 8; nf++) {
          int n = nf * 16 + lr;
          float x = acc[qf][nf][i] + p0[n] + bu2f(resid[(size_t)m * D_ + n]);
          v[nf] = x;
          sm += x;
          sq += x * x;
        }
#pragma unroll
        for (int msk = 1; msk < 16; msk <<= 1) {
          sm += __shfl_xor(sm, msk);
          sq += __shfl_xor(sq, msk);
        }
        float mu = sm * (1.f / 128.f);
        float var = sq * (1.f / 128.f) - mu * mu;
        float rs = rsqrtf(var + EPS_);
#pragma unroll
        for (int nf = 0; nf < 8; nf++) {
          int n = nf * 16 + lr;
          outb[(size_t)m * D_ + n] = f2bu((v[nf] - mu) * rs * p1[n] + p2[n]);
        }
      }
    }
  } else if constexpr (EPI == 1) {
    if (nt < 2) {  // q,k: scatter to [B,H,N,32]
#pragma unroll
      for (int qf = 0; qf < 2; qf++)
#pragma unroll
        for (int nf = 0; nf < 8; nf++)
#pragma unroll
          for (int i = 0; i < 4; i++) {
            int m = mt * 128 + w * 32 + qf * 16 + 4 * g + i;
            int n = nt * 128 + nf * 16 + lr;
            float vv = acc[qf][nf][i] + p0[n];
            int hh = (n >> 5) & 3, c = n & 31;
            int bb = m >> 11, tok = m & (N_ - 1);
            outb[(size_t)nt * 2097152 +
                 (((size_t)bb * H_ + hh) * N_ + tok) * HD_ + c] = f2bu(vv);
          }
    } else {  // v: transpose tile via LDS, store as [B,H,HD,N] coalesced
      __syncthreads();  // all waves done reading As
      u16 (*Vt)[KP] = (u16 (*)[KP])smem;  // [128 n][128 m] (+pad)
#pragma unroll
      for (int qf = 0; qf < 2; qf++)
#pragma unroll
        for (int nf = 0; nf < 8; nf++)
#pragma unroll
          for (int i = 0; i < 4; i++) {
            int m_l = w * 32 + qf * 16 + 4 * g + i;
            int n_l = nf * 16 + lr;
            Vt[n_l][m_l] = f2bu(acc[qf][nf][i] + p0[256 + n_l]);
          }
      __syncthreads();
      int bb = (mt * 128) >> 11, tok0 = (mt * 128) & (N_ - 1);
      for (int i2 = t; i2 < 2048; i2 += 256) {
        int row = i2 >> 4, seg = i2 & 15;  // row = h*32+c, 16 segs of 8 toks
        *(short8v*)(outb + (size_t)2 * 2097152 +
                    (((size_t)bb * H_ + (row >> 5)) * HD_ + (row & 31)) * N_ +
                    tok0 + seg * 8) = *(const short8v*)&Vt[row][seg * 8];
      }
    }
  } else {
#pragma unroll
    for (int qf = 0; qf < 2; qf++)
#pragma unroll
      for (int nf = 0; nf < 8; nf++)
#pragma unroll
        for (int i = 0; i < 4; i++) {
          int m = mt * 128 + w * 32 + qf * 16 + 4 * g + i;
          int nl = nf * 16 + lr;
          int n = nt * 128 + nl;
          float vv = acc[qf][nf][i];
          if constexpr (EPI == 0) {
            outb[(size_t)m * D_ + nl] = f2bu(vv + p0[n]);
          } else if constexpr (EPI == 2) {
            outb[(size_t)m * DFF_ + n] = f2bu(fmaxf(vv + p0[n], 0.f));
          } else {  // EPI == 4
            float r = fmaxf(vv * p1[n] + p2[n], 0.f);
            outf[((size_t)(m >> 9) * DOUT_ + n) * S_ + (m & (S_ - 1))] = r;
          }
        }
  }
}

// ---------------------------------------------------------------------------
// Flash attention, swapped-QK^T (R10/R11-verified). V arrives transposed in
// global ([B,H,HD,N]). Ones-row computes the softmax denominator inside the
// PV MFMA; defer-max (THR=8, log2 domain); P packed via v_cvt_pk_bf16_f32.
// ---------------------------------------------------------------------------
__global__ __launch_bounds__(256) void attn_mfma_kernel(
    const u16* __restrict__ qg, const u16* __restrict__ kg,
    const u16* __restrict__ vg, u16* __restrict__ o, int fpsnb, int s0, int s1,
    const float* fxyz, float* fdist, int* ffar, int* fidxo, float* fout0) {
  constexpr int ATTN_SMEM = 64 * 40 * 2 + 48 * 72 * 2 + 4 * 16 * 72 * 2;
  constexpr int SMEM = ATTN_SMEM > FPS_SMEM ? ATTN_SMEM : FPS_SMEM;
  __shared__ __align__(16) char smem[SMEM];
  if ((int)blockIdx.x < fpsnb) {
    fps_slice(smem, blockIdx.x, fxyz, fdist, ffar, fidxo, fout0, s0, s1);
    return;
  }
  const int t = threadIdx.x;
  const int w = t >> 6, lane = t & 63, g = lane >> 4, lr = lane & 15;
  u16 (*ks)[40] = (u16 (*)[40])smem;                      // K [64][40]
  u16 (*vt)[72] = (u16 (*)[72])(smem + 5120);             // V^T [48][72]
  u16 (*psw)[72] = (u16 (*)[72])(smem + 12032) + w * 16;  // P [16][72]/wave

  const int bid = blockIdx.x - fpsnb;
  const int qt = bid & 31;
  const int bh = bid >> 5;
  const int b = bh >> 2, h = bh & 3;
  const int qrow = qt * 64 + w * 16 + lr;  // this lane's q row

  // ones-row init: vt rows 32..47 (row 32 = bf16 1.0, rest 0), set once.
  for (int i = t; i < 16 * 72; i += 256) {
    int r = i / 72, c = i % 72;
    vt[32 + r][c] = (r == 0) ? (u16)0x3F80 : (u16)0;
  }

  // Q fragment: a[e]=Q[q=lr(+base)][8g+e]; serves as B-frag (=Q^T) for S^T.
  short8v aq = *(const short8v*)(qg + ((size_t)bh * N_ + qrow) * HD_ + 8 * g);

  const u16* kb = kg + (size_t)bh * N_ * HD_;
  const u16* vbt = vg + (size_t)bh * N_ * HD_;  // [HD][N] per bh

  const f32x4 fzero = {0.f, 0.f, 0.f, 0.f};
  float mrun = -INFINITY;
  f32x4 acco[3] = {fzero, fzero, fzero};  // O^T (d=16dt+4g+i, q=lr); [2]=l-row

  const int krow = t >> 2, kseg = (t & 3) * 8;  // K: 64 rows x 4 b128 segs
  const int vrow = t >> 3, vseg = (t & 7) * 8;  // V^T: 32 rows x 8 b128 segs

  for (int ch = 0; ch < 32; ch++) {
    __syncthreads();
    *(short8v*)(&ks[krow][kseg]) =
        *(const short8v*)(kb + (size_t)(ch * 64 + krow) * HD_ + kseg);
    *(short8v*)(&vt[vrow][vseg]) =
        *(const short8v*)(vbt + (size_t)vrow * N_ + ch * 64 + vseg);
    __syncthreads();

    // S^T = K x Q^T: st[kt][i] = S^T[key=16kt+4g+i][q=lr]  (log2 domain)
    f32x4 stv[4];
#pragma unroll
    for (int kt = 0; kt < 4; kt++) {
      short8v ak = *(const short8v*)(&ks[kt * 16 + lr][8 * g]);
      stv[kt] = __builtin_amdgcn_mfma_f32_16x16x32_bf16(ak, aq, fzero, 0, 0, 0);
    }

    // max over 16 in-reg values + 2 shfl (over g); defer-max THR=8
    float mx = -INFINITY;
#pragma unroll
    for (int kt = 0; kt < 4; kt++)
#pragma unroll
      for (int i = 0; i < 4; i++) mx = fmaxf(mx, stv[kt][i]);
    mx = fmaxf(mx, __shfl_xor(mx, 16));
    mx = fmaxf(mx, __shfl_xor(mx, 32));
    if (!__all(mx - mrun <= 8.0f)) {
      float nm = fmaxf(mrun, mx);
      float alpha = exp2f(mrun - nm);
      mrun = nm;
#pragma unroll
      for (int dt = 0; dt < 3; dt++)
#pragma unroll
        for (int i = 0; i < 4; i++) acco[dt][i] *= alpha;
    }
#pragma unroll
    for (int kt = 0; kt < 4; kt++) {
      float p0 = exp2f(stv[kt][0] - mrun);
      float p1 = exp2f(stv[kt][1] - mrun);
      float p2 = exp2f(stv[kt][2] - mrun);
      float p3 = exp2f(stv[kt][3] - mrun);
      u32 r01, r23;
      asm("v_cvt_pk_bf16_f32 %0, %1, %2" : "=v"(r01) : "v"(p0), "v"(p1));
      asm("v_cvt_pk_bf16_f32 %0, %1, %2" : "=v"(r23) : "v"(p2), "v"(p3));
      u64 pk = (u64)r01 | ((u64)r23 << 32);
      *(u64*)(&psw[lr][kt * 16 + 4 * g]) = pk;  // P[q=lr][k=16kt+4g..+3]
    }

    // O^T += V^T x P^T; row 32 of V^T = ones -> acco[2] row0 = sum_k P[q,k]
#pragma unroll
    for (int mc = 0; mc < 2; mc++) {
      short8v pb = *(const short8v*)(&psw[lr][mc * 32 + 8 * g]);
#pragma unroll
      for (int dt = 0; dt < 3; dt++) {
        short8v av = *(const short8v*)(&vt[dt * 16 + lr][mc * 32 + 8 * g]);
        acco[dt] = __builtin_amdgcn_mfma_f32_16x16x32_bf16(av, pb, acco[dt], 0, 0, 0);
      }
    }
  }

  // l for q=lr lives at lane (g=0, lr), acco[2][0]
  float lsum = __shfl(acco[2][0], lr);
  float rl = 1.0f / lsum;
#pragma unroll
  for (int dt = 0; dt < 2; dt++) {
    u64 pk = (u64)f2bu(acco[dt][0] * rl) | ((u64)f2bu(acco[dt][1] * rl) << 16) |
             ((u64)f2bu(acco[dt][2] * rl) << 32) |
             ((u64)f2bu(acco[dt][3] * rl) << 48);
    *(u64*)(o + ((size_t)b * N_ + qrow) * D_ + h * HD_ + dt * 16 + 4 * g) = pk;
  }
}

// ---------------------------------------------------------------------------
extern "C" void kernel_launch(void* const* d_in, const int* in_sizes, int n_in,
                              void* d_out, int out_size, void* d_ws, size_t ws_size,
                              hipStream_t stream) {
  const float* xyz    = (const float*)d_in[0];
  const float* points = (const float*)d_in[1];
  const float* Wp     = (const float*)d_in[2];
  const float* bp     = (const float*)d_in[3];
  const float* g1     = (const float*)d_in[4];
  const float* be1    = (const float*)d_in[5];
  const float* m1     = (const float*)d_in[6];
  const float* v1     = (const float*)d_in[7];
  const float* Wpos   = (const float*)d_in[8];
  const float* bpos   = (const float*)d_in[9];
  const float* Wq     = (const float*)d_in[10];
  const float* bq     = (const float*)d_in[11];
  const float* Wk     = (const float*)d_in[12];
  const float* bk     = (const float*)d_in[13];
  const float* Wv     = (const float*)d_in[14];
  const float* bv     = (const float*)d_in[15];
  const float* Wo     = (const float*)d_in[16];
  const float* bo     = (const float*)d_in[17];
  const float* lg1    = (const float*)d_in[18];
  const float* lb1    = (const float*)d_in[19];
  const float* W1     = (const float*)d_in[20];
  const float* b1     = (const float*)d_in[21];
  const float* W2     = (const float*)d_in[22];
  const float* b2p    = (const float*)d_in[23];
  const float* lg2    = (const float*)d_in[24];
  const float* lb2    = (const float*)d_in[25];
  const float* Wfc    = (const float*)d_in[26];
  const float* bfc    = (const float*)d_in[27];
  const float* g2     = (const float*)d_in[28];
  const float* bb2    = (const float*)d_in[29];
  const float* m2     = (const float*)d_in[30];
  const float* v2     = (const float*)d_in[31];

  float* out0 = (float*)d_out;               // [B,3,S]
  float* out1 = out0 + (size_t)B_ * 3 * S_;  // [B,Dout,S]

  char* ws = (char*)d_ws;
  int*   fps_idx = (int*)ws;                          // 16 KB
  u16*   wb      = (u16*)(ws + 16384);                // 249856 bf16
  float* fb      = (float*)(ws + 516096);             // 1024 f32 (ends 520192)
  float* dist_ws = (float*)(ws + 520192);             // B*2048 f32 = 64 KB
  int*   far_ws  = (int*)(ws + 585728);               // 8 ints
  const size_t MB = 1024 * 1024;
  u16* x     = (u16*)(ws + 1 * MB);    // [16384][128]
  u16* o     = (u16*)(ws + 5 * MB);    // [B,N,128]
  u16* x2    = (u16*)(ws + 9 * MB);    // [16384][128]
  u16* feats = (u16*)(ws + 13 * MB);   // [16384][128]
  u16* qb    = (u16*)(ws + 17 * MB);   // q|k [B,H,N,32], v [B,H,32,N]
  u16* h     = (u16*)(ws + 29 * MB);   // [16384][512]

  prep_kernel<<<980, 256, 0, stream>>>(Wq, bq, Wk, bk, Wv, bv, Wo, W1, W2, Wfc,
                                       bfc, Wp, bp, Wpos, bpos, g1, be1, m1, v1,
                                       g2, bb2, m2, v2, wb, fb);

  // FPS slices ride along the 6 pipeline kernels: 64|86|140|70|92|60 steps.
  gemm_k<96, 96, 1, 0><<<8 + 128, 256, 0, stream>>>(
      nullptr, wb + OW_CAT, points, xyz, nullptr, fb + 384, nullptr, nullptr,
      nullptr, x, nullptr, 1, 8, 0, 64, xyz, dist_ws, far_ws, fps_idx, out0);
  gemm_k<128, 128, 0, 1><<<8 + 384, 256, 0, stream>>>(
      x, wb + OW_QKV, nullptr, nullptr, nullptr, fb, nullptr, nullptr,
      nullptr, qb, nullptr, 3, 8, 64, 150, xyz, dist_ws, far_ws, fps_idx, out0);
  attn_mfma_kernel<<<8 + B_ * H_ * (N_ / 64), 256, 0, stream>>>(
      qb, qb + 2097152, qb + 2 * 2097152, o, 8, 150, 290, xyz, dist_ws, far_ws,
      fps_idx, out0);
  gemm_k<128, 128, 0, 3><<<8 + 128, 256, 0, stream>>>(
      o, wb + OW_O, nullptr, nullptr, nullptr, bo, lg1, lb1, x, x2, nullptr, 1,
      8, 290, 360, xyz, dist_ws, far_ws, fps_idx, out0);
  gemm_k<128, 128, 0, 2><<<8 + 512, 256, 0, stream>>>(
      x2, wb + OW_1, nullptr, nullptr, nullptr, b1, nullptr, nullptr,
      nullptr, h, nullptr, 4, 8, 360, 452, xyz, dist_ws, far_ws, fps_idx, out0);
  gemm_k<512, 128, 0, 3><<<8 + 128, 256, 0, stream>>>(
      h, wb + OW_2, nullptr, nullptr, nullptr, b2p, lg2, lb2, x2, feats,
      nullptr, 1, 8, 452, 512, xyz, dist_ws, far_ws, fps_idx, out0);
  gemm_k<160, 160, 2, 4><<<64, 256, 0, stream>>>(
      feats, wb + OW_FC, nullptr, xyz, fps_idx, nullptr, fb + 512, fb + 768,
      nullptr, nullptr, out1, 2, 0, 0, 0, nullptr, nullptr, nullptr, nullptr,
      nullptr);
}

// Round 15
// 340.161 us; speedup vs baseline: 1.1301x; 1.1301x over previous
//
#include <hip/hip_runtime.h>
#include <hip/hip_bf16.h>

#define B_    8
#define N_    2048
#define CIN_  64
#define D_    128
#define DFF_  512
#define DOUT_ 256
#define S_    512
#define H_    4
#define HD_   32
#define EPS_  1e-5f

typedef unsigned short u16;
typedef unsigned int u32;
typedef unsigned long long u64;
typedef __attribute__((ext_vector_type(8))) short short8v;  // 8 bf16
typedef __attribute__((ext_vector_type(4))) float f32x4;

__device__ __forceinline__ u16 f2bu(float f) {
  __hip_bfloat16 h = __float2bfloat16(f);
  return *(u16*)&h;
}
__device__ __forceinline__ float bu2f(u16 u) {
  __hip_bfloat16 h = *(__hip_bfloat16*)&u;
  return __bfloat162float(h);
}

// ---------------------------------------------------------------------------
// FPS slice (4 waves, 8 pts/lane): steps [s0,s1) for batch b, hosted as
// extra blocks in the pipeline kernels (state in d_ws). numpy-exact f32
// arithmetic, first-occurrence argmax. R11-proven variant (DPP value-max +
// ballot + readlane tail; R14's tuple-DPP was slower).
// ---------------------------------------------------------------------------
#define FPS_SMEM 320

template <int CTRL, int RM>
__device__ __forceinline__ float dppmax(float v) {
  int m = __builtin_amdgcn_update_dpp(__float_as_int(v), __float_as_int(v),
                                      CTRL, RM, 0xF, true);
  return fmaxf(v, __int_as_float(m));
}

__device__ __forceinline__ void fps_slice(
    char* smem, int b, const float* __restrict__ xyz,
    float* __restrict__ dist_ws, int* __restrict__ far_ws,
    int* __restrict__ idx_out, float* __restrict__ out0, int s0, int s1) {
  u64* keys = (u64*)smem;            // [2][4]
  float* crd = (float*)(smem + 64);  // [2][4][3]
  const int t = threadIdx.x, w = t >> 6, lane = t & 63;
  const float* xb = xyz + (size_t)b * 3 * N_;
  const int base = (w * 64 + lane) * 8;
  float* dw = dist_ws + b * N_;
  float px[8], py[8], pz[8], dist[8];
#pragma unroll
  for (int j = 0; j < 8; j++) {
    px[j] = xb[base + j];
    py[j] = xb[N_ + base + j];
    pz[j] = xb[2 * N_ + base + j];
    dist[j] = 1e10f;
  }
  if (s0 != 0) {
#pragma unroll
    for (int j = 0; j < 8; j++) dist[j] = dw[base + j];
  }
  int far = (s0 == 0) ? 0 : far_ws[b];
  float cx = xb[far], cy = xb[N_ + far], cz = xb[2 * N_ + far];
  for (int s = s0; s < s1; s++) {
    if (t == 0) {
      idx_out[b * S_ + s] = far;
      out0[(size_t)b * 3 * S_ + s] = cx;
      out0[(size_t)b * 3 * S_ + S_ + s] = cy;
      out0[(size_t)b * 3 * S_ + 2 * S_ + s] = cz;
    }
    float best = -1.0f, bx = 0.f, by = 0.f, bz = 0.f;
    int bestp = 0;
#pragma unroll
    for (int j = 0; j < 8; j++) {
      float dx = __fsub_rn(px[j], cx);
      float dy = __fsub_rn(py[j], cy);
      float dz = __fsub_rn(pz[j], cz);
      float d = __fadd_rn(__fadd_rn(__fmul_rn(dx, dx), __fmul_rn(dy, dy)),
                          __fmul_rn(dz, dz));
      float nd = fminf(dist[j], d);
      dist[j] = nd;
      if (nd > best) {
        best = nd; bestp = base + j;  // ascending j: first max
        bx = px[j]; by = py[j]; bz = pz[j];
      }
    }
    // wave-wide max (value) via DPP; lane 63 holds the wave max
    float m = best;
    m = dppmax<0x111, 0xF>(m);  // row_shr:1
    m = dppmax<0x112, 0xF>(m);  // row_shr:2
    m = dppmax<0x114, 0xF>(m);  // row_shr:4
    m = dppmax<0x118, 0xF>(m);  // row_shr:8
    m = dppmax<0x142, 0xA>(m);  // row_bcast:15
    m = dppmax<0x143, 0xC>(m);  // row_bcast:31
    float M = __int_as_float(__builtin_amdgcn_readlane(__float_as_int(m), 63));
    u64 mask = __ballot(best == M);
    int wl = __ffsll((long long)mask) - 1;  // first lane = smallest point idx
    if (lane == wl) {
      int sb = (s & 1) * 4 + w;
      keys[sb] = ((u64)__float_as_uint(M) << 32) |
                 (unsigned)(0xFFFFFFFFu - (unsigned)bestp);
      crd[sb * 3 + 0] = bx;
      crd[sb * 3 + 1] = by;
      crd[sb * 3 + 2] = bz;
    }
    asm volatile("s_waitcnt lgkmcnt(0)" ::: "memory");
    __builtin_amdgcn_s_barrier();
    asm volatile("" ::: "memory");
    const int q0 = (s & 1) * 4;
    u64 k0 = keys[q0], k1 = keys[q0 + 1], k2 = keys[q0 + 2], k3 = keys[q0 + 3];
    const f32x4* crd4 = (const f32x4*)(crd + q0 * 3);
    f32x4 v0 = crd4[0], v1 = crd4[1], v2 = crd4[2];
    // candidates: c0=(v0.xyz) c1=(v0.w,v1.xy) c2=(v1.zw,v2.x) c3=(v2.yzw)
    bool c01 = k0 >= k1;
    u64 ka = c01 ? k0 : k1;
    float xa = c01 ? v0[0] : v0[3], ya = c01 ? v0[1] : v1[0],
          za = c01 ? v0[2] : v1[1];
    bool c23 = k2 >= k3;
    u64 kb = c23 ? k2 : k3;
    float xv = c23 ? v1[2] : v2[1], yv = c23 ? v1[3] : v2[2],
          zv = c23 ? v2[0] : v2[3];
    bool cf = ka >= kb;
    u64 kk = cf ? ka : kb;
    cx = cf ? xa : xv; cy = cf ? ya : yv; cz = cf ? za : zv;
    far = (int)(0xFFFFFFFFu - (unsigned)kk);
  }
#pragma unroll
  for (int j = 0; j < 8; j++) dw[base + j] = dist[j];
  if (t == 0) far_ws[b] = far;
}

// ---------------------------------------------------------------------------
// Weight prep (+ FPS co-blocks at blockIdx < 8 hosting steps [0,12) —
// hidden under prep's ~8 us of work). SC folds 1/sqrt(hd) AND log2(e).
// ---------------------------------------------------------------------------
#define OW_QKV 0
#define OW_O   49152
#define OW_1   65536
#define OW_2   131072
#define OW_FC  196608
#define OW_CAT 237568
#define NW_TOT 249856

__global__ __launch_bounds__(256) void prep_kernel(
    const float* __restrict__ Wq, const float* __restrict__ bq,
    const float* __restrict__ Wk, const float* __restrict__ bk,
    const float* __restrict__ Wv, const float* __restrict__ bv,
    const float* __restrict__ Wo, const float* __restrict__ W1,
    const float* __restrict__ W2, const float* __restrict__ Wfc,
    const float* __restrict__ bfc, const float* __restrict__ Wp,
    const float* __restrict__ bp, const float* __restrict__ Wpos,
    const float* __restrict__ bpos, const float* __restrict__ g1,
    const float* __restrict__ be1, const float* __restrict__ m1,
    const float* __restrict__ v1, const float* __restrict__ g2,
    const float* __restrict__ bb2, const float* __restrict__ m2,
    const float* __restrict__ v2, u16* __restrict__ wb,
    float* __restrict__ fb, int fpsnb, int s0, int s1, const float* fxyz,
    float* fdist, int* ffar, int* fidxo, float* fout0) {
  __shared__ __align__(16) char smem[FPS_SMEM];
  if ((int)blockIdx.x < fpsnb) {
    fps_slice(smem, blockIdx.x, fxyz, fdist, ffar, fidxo, fout0, s0, s1);
    return;
  }
  const float SC = 0.1767766952966369f * 1.4426950408889634f;  // /sqrt(hd)*log2e
  int i = ((int)blockIdx.x - fpsnb) * 256 + threadIdx.x;
  if (i < OW_O) {  // Wqkv [384][128]
    int n = i >> 7, k = i & 127;
    float v = (n < 128) ? Wq[i] * SC
                        : (n < 256) ? Wk[(n - 128) * 128 + k]
                                    : Wv[(n - 256) * 128 + k];
    wb[OW_QKV + i] = f2bu(v);
  } else if (i < OW_1) {
    wb[i] = f2bu(Wo[i - OW_O]);
  } else if (i < OW_2) {
    wb[i] = f2bu(W1[i - OW_1]);
  } else if (i < OW_FC) {
    wb[i] = f2bu(W2[i - OW_2]);
  } else if (i < OW_CAT) {  // Wfc [256][160] (pad 131->160)
    int j = i - OW_FC;
    int n = j / 160, c = j % 160;
    wb[i] = f2bu(c < 131 ? Wfc[n * 131 + c] : 0.f);
  } else if (i < NW_TOT) {  // Wcat [128][96]: BN1-scaled Wp | Wpos | 0
    int j = i - OW_CAT;
    int d = j / 96, c = j % 96;
    float v;
    if (c < 64) v = Wp[d * 64 + c] * (g1[d] * rsqrtf(v1[d] + EPS_));
    else if (c < 67) v = Wpos[d * 3 + (c - 64)];
    else v = 0.f;
    wb[i] = f2bu(v);
  } else if (i < NW_TOT + 384) {  // bqkv
    int n = i - NW_TOT;
    fb[n] = (n < 128) ? bq[n] * SC : (n < 256) ? bk[n - 128] : bv[n - 256];
  } else if (i < NW_TOT + 512) {  // bias_x
    int d = i - (NW_TOT + 384);
    float s1 = g1[d] * rsqrtf(v1[d] + EPS_);
    fb[384 + d] = (bp[d] - m1[d]) * s1 + be1[d] + bpos[d];
  } else if (i < NW_TOT + 768) {  // fc_scale
    int n = i - (NW_TOT + 512);
    fb[512 + n] = g2[n] * rsqrtf(v2[n] + EPS_);
  } else if (i < NW_TOT + 1024) {  // fc_shift
    int n = i - (NW_TOT + 768);
    float s = g2[n] * rsqrtf(v2[n] + EPS_);
    fb[768 + n] = bfc[n] * s + bb2[n] - m2[n] * s;
  }
}

// ---------------------------------------------------------------------------
// Tiled bf16 MFMA GEMM template (+ FPS co-blocks at blockIdx < fpsnb).
// C[128 x 128] tile per block, 4 waves, 16x16x32 MFMA. (R9-R11 verified.)
// LDS padded to 84 KB (R11): FPS co-blocks get dedicated CUs; GEMM hosts
// are slice-bound so the 1-block/CU cost is hidden.
// ---------------------------------------------------------------------------
template <int K, int KC, int ASTAGE, int EPI>
__global__ __launch_bounds__(256) void gemm_k(
    const u16* __restrict__ A, const u16* __restrict__ W,
    const float* __restrict__ srcf0, const float* __restrict__ srcf1,
    const int* __restrict__ fidx, const float* __restrict__ p0,
    const float* __restrict__ p1, const float* __restrict__ p2,
    const u16* __restrict__ resid, u16* __restrict__ outb,
    float* __restrict__ outf, int ntn, int fpsnb, int s0, int s1,
    const float* fxyz, float* fdist, int* ffar, int* fidxo, float* fout0) {
  constexpr int KP = KC + 8;
  constexpr int GEMM_SMEM = 2 * 128 * KP * 2;
  constexpr int SMEM = GEMM_SMEM > 86016 ? GEMM_SMEM : 86016;  // CU fence
  __shared__ __align__(16) char smem[SMEM];
  if ((int)blockIdx.x < fpsnb) {
    fps_slice(smem, blockIdx.x, fxyz, fdist, ffar, fidxo, fout0, s0, s1);
    return;
  }
  u16 (*As)[KP] = (u16 (*)[KP])smem;
  u16 (*Ws)[KP] = (u16 (*)[KP])(smem + 128 * KP * 2);
  const int bid = blockIdx.x - fpsnb;
  const int mt = bid / ntn, nt = bid % ntn;
  const int t = threadIdx.x, w = t >> 6, lane = t & 63;
  const int g = lane >> 4, lr = lane & 15;

  f32x4 acc[2][8];
#pragma unroll
  for (int qf = 0; qf < 2; qf++)
#pragma unroll
    for (int nf = 0; nf < 8; nf++) acc[qf][nf] = {0.f, 0.f, 0.f, 0.f};

  for (int kc = 0; kc < K / KC; kc++) {
    __syncthreads();
    for (int i = t; i < 128 * (KC / 8); i += 256) {
      int row = i / (KC / 8), c8 = i % (KC / 8);
      *(short8v*)&Ws[row][c8 * 8] =
          *(const short8v*)(W + (size_t)(nt * 128 + row) * K + kc * KC + c8 * 8);
    }
    if constexpr (ASTAGE == 0) {
      for (int i = t; i < 128 * (KC / 8); i += 256) {
        int row = i / (KC / 8), c8 = i % (KC / 8);
        *(short8v*)&As[row][c8 * 8] =
            *(const short8v*)(A + (size_t)(mt * 128 + row) * K + kc * KC + c8 * 8);
      }
    } else if constexpr (ASTAGE == 1) {
      int bb = (mt * 128) >> 11, n0 = (mt * 128) & (N_ - 1);
      for (int i = t; i < 96 * 128; i += 256) {
        int c = i >> 7, n = i & 127;
        float v;
        if (c < 64) v = srcf0[((size_t)bb * CIN_ + c) * N_ + n0 + n];
        else if (c < 67) v = srcf1[((size_t)bb * 3 + (c - 64)) * N_ + n0 + n];
        else v = 0.f;
        As[n][c] = f2bu(v);
      }
    } else {  // ASTAGE == 2
      int bb = (mt * 128) >> 9, sq0 = (mt * 128) & (S_ - 1);
      for (int i = t; i < 128 * 20; i += 256) {
        int row = i / 20, c8 = i % 20;
        int id = fidx[bb * S_ + sq0 + row];
        short8v val;
        if (c8 < 16) {
          val = *(const short8v*)(A + ((size_t)bb * N_ + id) * D_ + c8 * 8);
        } else if (c8 == 16) {
          val = short8v{0, 0, 0, 0, 0, 0, 0, 0};
          val[0] = (short)f2bu(srcf1[((size_t)bb * 3 + 0) * N_ + id]);
          val[1] = (short)f2bu(srcf1[((size_t)bb * 3 + 1) * N_ + id]);
          val[2] = (short)f2bu(srcf1[((size_t)bb * 3 + 2) * N_ + id]);
        } else {
          val = short8v{0, 0, 0, 0, 0, 0, 0, 0};
        }
        *(short8v*)&As[row][c8 * 8] = val;
      }
    }
    __syncthreads();
#pragma unroll
    for (int ks = 0; ks < KC / 32; ks++) {
      short8v a0 = *(const short8v*)&As[w * 32 + lr][ks * 32 + 8 * g];
      short8v a1 = *(const short8v*)&As[w * 32 + 16 + lr][ks * 32 + 8 * g];
#pragma unroll
      for (int nf = 0; nf < 8; nf++) {
        short8v bb = *(const short8v*)&Ws[nf * 16 + lr][ks * 32 + 8 * g];
        acc[0][nf] = __builtin_amdgcn_mfma_f32_16x16x32_bf16(a0, bb, acc[0][nf], 0, 0, 0);
        acc[1][nf] = __builtin_amdgcn_mfma_f32_16x16x32_bf16(a1, bb, acc[1][nf], 0, 0, 0);
      }
    }
  }

  if constexpr (EPI == 3) {  // bias + residual + LayerNorm (ntn==1)
#pragma unroll
    for (int qf = 0; qf < 2; qf++) {
#pragma unroll
      for (int i = 0; i < 4; i++) {
        int m = mt * 128 + w * 32 + qf * 16 + 4 * g + i;
        float v[8], sm = 0.f, sq = 0.f;
#pragma unroll
        for (int nf = 0; nf < 8; nf++) {
          int n = nf * 16 + lr;
          float x = acc[qf][nf][i] + p0[n] + bu2f(resid[(size_t)m * D_ + n]);
          v[nf] = x;
          sm += x;
          sq += x * x;
        }
#pragma unroll
        for (int msk = 1; msk < 16; msk <<= 1) {
          sm += __shfl_xor(sm, msk);
          sq += __shfl_xor(sq, msk);
        }
        float mu = sm * (1.f / 128.f);
        float var = sq * (1.f / 128.f) - mu * mu;
        float rs = rsqrtf(var + EPS_);
#pragma unroll
        for (int nf = 0; nf < 8; nf++) {
          int n = nf * 16 + lr;
          outb[(size_t)m * D_ + n] = f2bu((v[nf] - mu) * rs * p1[n] + p2[n]);
        }
      }
    }
  } else if constexpr (EPI == 1) {
    if (nt < 2) {  // q,k: scatter to [B,H,N,32]
#pragma unroll
      for (int qf = 0; qf < 2; qf++)
#pragma unroll
        for (int nf = 0; nf < 8; nf++)
#pragma unroll
          for (int i = 0; i < 4; i++) {
            int m = mt * 128 + w * 32 + qf * 16 + 4 * g + i;
            int n = nt * 128 + nf * 16 + lr;
            float vv = acc[qf][nf][i] + p0[n];
            int hh = (n >> 5) & 3, c = n & 31;
            int bb = m >> 11, tok = m & (N_ - 1);
            outb[(size_t)nt * 2097152 +
                 (((size_t)bb * H_ + hh) * N_ + tok) * HD_ + c] = f2bu(vv);
          }
    } else {  // v: transpose tile via LDS, store as [B,H,HD,N] coalesced
      __syncthreads();  // all waves done reading As
      u16 (*Vt)[KP] = (u16 (*)[KP])smem;  // [128 n][128 m] (+pad)
#pragma unroll
      for (int qf = 0; qf < 2; qf++)
#pragma unroll
        for (int nf = 0; nf < 8; nf++)
#pragma unroll
          for (int i = 0; i < 4; i++) {
            int m_l = w * 32 + qf * 16 + 4 * g + i;
            int n_l = nf * 16 + lr;
            Vt[n_l][m_l] = f2bu(acc[qf][nf][i] + p0[256 + n_l]);
          }
      __syncthreads();
      int bb = (mt * 128) >> 11, tok0 = (mt * 128) & (N_ - 1);
      for (int i2 = t; i2 < 2048; i2 += 256) {
        int row = i2 >> 4, seg = i2 & 15;  // row = h*32+c, 16 segs of 8 toks
        *(short8v*)(outb + (size_t)2 * 2097152 +
                    (((size_t)bb * H_ + (row >> 5)) * HD_ + (row & 31)) * N_ +
                    tok0 + seg * 8) = *(const short8v*)&Vt[row][seg * 8];
      }
    }
  } else {
#pragma unroll
    for (int qf = 0; qf < 2; qf++)
#pragma unroll
      for (int nf = 0; nf < 8; nf++)
#pragma unroll
        for (int i = 0; i < 4; i++) {
          int m = mt * 128 + w * 32 + qf * 16 + 4 * g + i;
          int nl = nf * 16 + lr;
          int n = nt * 128 + nl;
          float vv = acc[qf][nf][i];
          if constexpr (EPI == 0) {
            outb[(size_t)m * D_ + nl] = f2bu(vv + p0[n]);
          } else if constexpr (EPI == 2) {
            outb[(size_t)m * DFF_ + n] = f2bu(fmaxf(vv + p0[n], 0.f));
          } else {  // EPI == 4
            float r = fmaxf(vv * p1[n] + p2[n], 0.f);
            outf[((size_t)(m >> 9) * DOUT_ + n) * S_ + (m & (S_ - 1))] = r;
          }
        }
  }
}

// ---------------------------------------------------------------------------
// Flash attention, swapped-QK^T (R10/R11-verified). V arrives transposed in
// global ([B,H,HD,N]). Ones-row computes the softmax denominator inside the
// PV MFMA; defer-max (THR=8, log2 domain); P packed via v_cvt_pk_bf16_f32.
// ---------------------------------------------------------------------------
__global__ __launch_bounds__(256) void attn_mfma_kernel(
    const u16* __restrict__ qg, const u16* __restrict__ kg,
    const u16* __restrict__ vg, u16* __restrict__ o, int fpsnb, int s0, int s1,
    const float* fxyz, float* fdist, int* ffar, int* fidxo, float* fout0) {
  constexpr int ATTN_SMEM = 64 * 40 * 2 + 48 * 72 * 2 + 4 * 16 * 72 * 2;
  constexpr int SMEM = ATTN_SMEM > FPS_SMEM ? ATTN_SMEM : FPS_SMEM;
  __shared__ __align__(16) char smem[SMEM];
  if ((int)blockIdx.x < fpsnb) {
    fps_slice(smem, blockIdx.x, fxyz, fdist, ffar, fidxo, fout0, s0, s1);
    return;
  }
  const int t = threadIdx.x;
  const int w = t >> 6, lane = t & 63, g = lane >> 4, lr = lane & 15;
  u16 (*ks)[40] = (u16 (*)[40])smem;                      // K [64][40]
  u16 (*vt)[72] = (u16 (*)[72])(smem + 5120);             // V^T [48][72]
  u16 (*psw)[72] = (u16 (*)[72])(smem + 12032) + w * 16;  // P [16][72]/wave

  const int bid = blockIdx.x - fpsnb;
  const int qt = bid & 31;
  const int bh = bid >> 5;
  const int b = bh >> 2, h = bh & 3;
  const int qrow = qt * 64 + w * 16 + lr;  // this lane's q row

  // ones-row init: vt rows 32..47 (row 32 = bf16 1.0, rest 0), set once.
  for (int i = t; i < 16 * 72; i += 256) {
    int r = i / 72, c = i % 72;
    vt[32 + r][c] = (r == 0) ? (u16)0x3F80 : (u16)0;
  }

  // Q fragment: a[e]=Q[q=lr(+base)][8g+e]; serves as B-frag (=Q^T) for S^T.
  short8v aq = *(const short8v*)(qg + ((size_t)bh * N_ + qrow) * HD_ + 8 * g);

  const u16* kb = kg + (size_t)bh * N_ * HD_;
  const u16* vbt = vg + (size_t)bh * N_ * HD_;  // [HD][N] per bh

  const f32x4 fzero = {0.f, 0.f, 0.f, 0.f};
  float mrun = -INFINITY;
  f32x4 acco[3] = {fzero, fzero, fzero};  // O^T (d=16dt+4g+i, q=lr); [2]=l-row

  const int krow = t >> 2, kseg = (t & 3) * 8;  // K: 64 rows x 4 b128 segs
  const int vrow = t >> 3, vseg = (t & 7) * 8;  // V^T: 32 rows x 8 b128 segs

  for (int ch = 0; ch < 32; ch++) {
    __syncthreads();
    *(short8v*)(&ks[krow][kseg]) =
        *(const short8v*)(kb + (size_t)(ch * 64 + krow) * HD_ + kseg);
    *(short8v*)(&vt[vrow][vseg]) =
        *(const short8v*)(vbt + (size_t)vrow * N_ + ch * 64 + vseg);
    __syncthreads();

    // S^T = K x Q^T: st[kt][i] = S^T[key=16kt+4g+i][q=lr]  (log2 domain)
    f32x4 stv[4];
#pragma unroll
    for (int kt = 0; kt < 4; kt++) {
      short8v ak = *(const short8v*)(&ks[kt * 16 + lr][8 * g]);
      stv[kt] = __builtin_amdgcn_mfma_f32_16x16x32_bf16(ak, aq, fzero, 0, 0, 0);
    }

    // max over 16 in-reg values + 2 shfl (over g); defer-max THR=8
    float mx = -INFINITY;
#pragma unroll
    for (int kt = 0; kt < 4; kt++)
#pragma unroll
      for (int i = 0; i < 4; i++) mx = fmaxf(mx, stv[kt][i]);
    mx = fmaxf(mx, __shfl_xor(mx, 16));
    mx = fmaxf(mx, __shfl_xor(mx, 32));
    if (!__all(mx - mrun <= 8.0f)) {
      float nm = fmaxf(mrun, mx);
      float alpha = exp2f(mrun - nm);
      mrun = nm;
#pragma unroll
      for (int dt = 0; dt < 3; dt++)
#pragma unroll
        for (int i = 0; i < 4; i++) acco[dt][i] *= alpha;
    }
#pragma unroll
    for (int kt = 0; kt < 4; kt++) {
      float p0 = exp2f(stv[kt][0] - mrun);
      float p1 = exp2f(stv[kt][1] - mrun);
      float p2 = exp2f(stv[kt][2] - mrun);
      float p3 = exp2f(stv[kt][3] - mrun);
      u32 r01, r23;
      asm("v_cvt_pk_bf16_f32 %0, %1, %2" : "=v"(r01) : "v"(p0), "v"(p1));
      asm("v_cvt_pk_bf16_f32 %0, %1, %2" : "=v"(r23) : "v"(p2), "v"(p3));
      u64 pk = (u64)r01 | ((u64)r23 << 32);
      *(u64*)(&psw[lr][kt * 16 + 4 * g]) = pk;  // P[q=lr][k=16kt+4g..+3]
    }

    // O^T += V^T x P^T; row 32 of V^T = ones -> acco[2] row0 = sum_k P[q,k]
#pragma unroll
    for (int mc = 0; mc < 2; mc++) {
      short8v pb = *(const short8v*)(&psw[lr][mc * 32 + 8 * g]);
#pragma unroll
      for (int dt = 0; dt < 3; dt++) {
        short8v av = *(const short8v*)(&vt[dt * 16 + lr][mc * 32 + 8 * g]);
        acco[dt] = __builtin_amdgcn_mfma_f32_16x16x32_bf16(av, pb, acco[dt], 0, 0, 0);
      }
    }
  }

  // l for q=lr lives at lane (g=0, lr), acco[2][0]
  float lsum = __shfl(acco[2][0], lr);
  float rl = 1.0f / lsum;
#pragma unroll
  for (int dt = 0; dt < 2; dt++) {
    u64 pk = (u64)f2bu(acco[dt][0] * rl) | ((u64)f2bu(acco[dt][1] * rl) << 16) |
             ((u64)f2bu(acco[dt][2] * rl) << 32) |
             ((u64)f2bu(acco[dt][3] * rl) << 48);
    *(u64*)(o + ((size_t)b * N_ + qrow) * D_ + h * HD_ + dt * 16 + 4 * g) = pk;
  }
}

// ---------------------------------------------------------------------------
extern "C" void kernel_launch(void* const* d_in, const int* in_sizes, int n_in,
                              void* d_out, int out_size, void* d_ws, size_t ws_size,
                              hipStream_t stream) {
  const float* xyz    = (const float*)d_in[0];
  const float* points = (const float*)d_in[1];
  const float* Wp     = (const float*)d_in[2];
  const float* bp     = (const float*)d_in[3];
  const float* g1     = (const float*)d_in[4];
  const float* be1    = (const float*)d_in[5];
  const float* m1     = (const float*)d_in[6];
  const float* v1     = (const float*)d_in[7];
  const float* Wpos   = (const float*)d_in[8];
  const float* bpos   = (const float*)d_in[9];
  const float* Wq     = (const float*)d_in[10];
  const float* bq     = (const float*)d_in[11];
  const float* Wk     = (const float*)d_in[12];
  const float* bk     = (const float*)d_in[13];
  const float* Wv     = (const float*)d_in[14];
  const float* bv     = (const float*)d_in[15];
  const float* Wo     = (const float*)d_in[16];
  const float* bo     = (const float*)d_in[17];
  const float* lg1    = (const float*)d_in[18];
  const float* lb1    = (const float*)d_in[19];
  const float* W1     = (const float*)d_in[20];
  const float* b1     = (const float*)d_in[21];
  const float* W2     = (const float*)d_in[22];
  const float* b2p    = (const float*)d_in[23];
  const float* lg2    = (const float*)d_in[24];
  const float* lb2    = (const float*)d_in[25];
  const float* Wfc    = (const float*)d_in[26];
  const float* bfc    = (const float*)d_in[27];
  const float* g2     = (const float*)d_in[28];
  const float* bb2    = (const float*)d_in[29];
  const float* m2     = (const float*)d_in[30];
  const float* v2     = (const float*)d_in[31];

  float* out0 = (float*)d_out;               // [B,3,S]
  float* out1 = out0 + (size_t)B_ * 3 * S_;  // [B,Dout,S]

  char* ws = (char*)d_ws;
  int*   fps_idx = (int*)ws;                          // 16 KB
  u16*   wb      = (u16*)(ws + 16384);                // 249856 bf16
  float* fb      = (float*)(ws + 516096);             // 1024 f32 (ends 520192)
  float* dist_ws = (float*)(ws + 520192);             // B*2048 f32 = 64 KB
  int*   far_ws  = (int*)(ws + 585728);               // 8 ints
  const size_t MB = 1024 * 1024;
  u16* x     = (u16*)(ws + 1 * MB);    // [16384][128]
  u16* o     = (u16*)(ws + 5 * MB);    // [B,N,128]
  u16* x2    = (u16*)(ws + 9 * MB);    // [16384][128]
  u16* feats = (u16*)(ws + 13 * MB);   // [16384][128]
  u16* qb    = (u16*)(ws + 17 * MB);   // q|k [B,H,N,32], v [B,H,32,N]
  u16* h     = (u16*)(ws + 29 * MB);   // [16384][512]

  // FPS slices: prep 12 | xfeat 64 | qkv 86 | attn 124 | oln1 74 | ffn1 92
  //             | ffn2 60  (sum = 512)
  prep_kernel<<<8 + 980, 256, 0, stream>>>(
      Wq, bq, Wk, bk, Wv, bv, Wo, W1, W2, Wfc, bfc, Wp, bp, Wpos, bpos, g1,
      be1, m1, v1, g2, bb2, m2, v2, wb, fb, 8, 0, 12, xyz, dist_ws, far_ws,
      fps_idx, out0);
  gemm_k<96, 96, 1, 0><<<8 + 128, 256, 0, stream>>>(
      nullptr, wb + OW_CAT, points, xyz, nullptr, fb + 384, nullptr, nullptr,
      nullptr, x, nullptr, 1, 8, 12, 76, xyz, dist_ws, far_ws, fps_idx, out0);
  gemm_k<128, 128, 0, 1><<<8 + 384, 256, 0, stream>>>(
      x, wb + OW_QKV, nullptr, nullptr, nullptr, fb, nullptr, nullptr,
      nullptr, qb, nullptr, 3, 8, 76, 162, xyz, dist_ws, far_ws, fps_idx, out0);
  attn_mfma_kernel<<<8 + B_ * H_ * (N_ / 64), 256, 0, stream>>>(
      qb, qb + 2097152, qb + 2 * 2097152, o, 8, 162, 286, xyz, dist_ws, far_ws,
      fps_idx, out0);
  gemm_k<128, 128, 0, 3><<<8 + 128, 256, 0, stream>>>(
      o, wb + OW_O, nullptr, nullptr, nullptr, bo, lg1, lb1, x, x2, nullptr, 1,
      8, 286, 360, xyz, dist_ws, far_ws, fps_idx, out0);
  gemm_k<128, 128, 0, 2><<<8 + 512, 256, 0, stream>>>(
      x2, wb + OW_1, nullptr, nullptr, nullptr, b1, nullptr, nullptr,
      nullptr, h, nullptr, 4, 8, 360, 452, xyz, dist_ws, far_ws, fps_idx, out0);
  gemm_k<512, 128, 0, 3><<<8 + 128, 256, 0, stream>>>(
      h, wb + OW_2, nullptr, nullptr, nullptr, b2p, lg2, lb2, x2, feats,
      nullptr, 1, 8, 452, 512, xyz, dist_ws, far_ws, fps_idx, out0);
  gemm_k<160, 160, 2, 4><<<64, 256, 0, stream>>>(
      feats, wb + OW_FC, nullptr, xyz, fps_idx, nullptr, fb + 512, fb + 768,
      nullptr, nullptr, out1, 2, 0, 0, 0, nullptr, nullptr, nullptr, nullptr,
      nullptr);
}